// Round 6
// baseline (230.548 us; speedup 1.0000x reference)
//
#include <hip/hip_runtime.h>
#include <math.h>

typedef unsigned short u16;
typedef unsigned int   u32;
typedef __attribute__((ext_vector_type(8))) short short8;
typedef __attribute__((ext_vector_type(4))) float f32x4;

namespace {
constexpr int Bb = 32, Nn = 32, Ll = 512, Mm = 64, Ff = 64;
constexpr int TL  = 32;           // K-tile in l (= one MFMA K step)
constexpr int NT  = Ll / TL;      // 16
constexpr int TLP = 40;           // padded row (u16): 80B stride, conflict-free (r3-measured 0)
constexpr float EPSV = 1e-8f;
}

__device__ __forceinline__ u16 bf16rne(float x) {
    u32 u = __float_as_uint(x);
    return (u16)((u + 0x7fffu + ((u >> 16) & 1u)) >> 16);
}
__device__ __forceinline__ float bf16tof(u16 h) {
    return __uint_as_float(((u32)h) << 16);
}

// ---------------------------------------------------------------------------
// Fused r3-shape kernel: block = (b-pair, n), grid 512, 256 thr, 60 KB LDS
// double-buffer -> 2 blocks/CU (8 waves).  Depth-2 register prefetch: loads
// for tile t+2 issue at iter t; staging of tile t+1 consumes regs loaded a
// full iteration earlier.  Alpha computed in-kernel (1 exp + 1 rcp / elem,
// m-major), denominator reduced post-loop in LDS (aliased on stage buf 0).
// ---------------------------------------------------------------------------
__global__ __launch_bounds__(256, 2)
void wagg_fused(const float* __restrict__ x_aug,
                const float* __restrict__ t_in,
                const float* __restrict__ t_left,
                const float* __restrict__ t_right,
                const float* __restrict__ kappa,
                float* __restrict__ out)
{
    const int n   = blockIdx.x & 31;
    const int b0  = (blockIdx.x >> 5) * 2;
    const int tid = threadIdx.x;

    __shared__ u16 ah_s[2][Mm * TLP];        // alpha-hi [m][l]      5 KB/stage
    __shared__ u16 al_s[2][Mm * TLP];        // alpha-lo             5 KB/stage
    __shared__ u16 xh_s[2][2 * Ff * TLP];    // x-hi  [b][f][l]     10 KB/stage
    __shared__ u16 xl_s[2][2 * Ff * TLP];    // x-lo                total 60 KB

    // ---- staging ids ----
    const int fq  = tid & 15;                // f quad (f = 4*fq + j)
    const int lp2 = tid >> 4;                // 0..15 -> l rows 2*lp2, 2*lp2+1
    const int am  = tid & 63;                // alpha row m
    const int aq  = tid >> 6;                // alpha l-octet 0..3

    // ---- compute ids (r3-proven mapping) ----
    const int lane = tid & 63;
    const int w    = tid >> 6;
    const int bw   = w & 1;                  // which b this wave computes
    const int mg   = w >> 1;                 // m-half
    const int q    = lane >> 4;              // k-chunk / D-row-quad
    const int c    = lane & 15;              // A/B row select / D-col

    const float* xb0 = x_aug + (size_t)(b0 * Nn + n) * (Ll * Ff);
    const float* xb1 = x_aug + (size_t)((b0 + 1) * Nn + n) * (Ll * Ff);

    const float kap = kappa[n];
    const float kk  = fmaxf(kap, 0.0f) + log1pf(expf(-fabsf(kap))); // softplus
    const float ik  = 1.0f / kk;
    const float tlv = t_left [n * Mm + am];
    const float trv = t_right[n * Mm + am];
    const float Ac  = __expf(-trv * ik);     // e^{-tr/k}
    const float Bc  = __expf( tlv * ik);     // e^{+tl/k}

    f32x4 acc[2][4];
    #pragma unroll
    for (int mi = 0; mi < 2; ++mi)
        #pragma unroll
        for (int ft = 0; ft < 4; ++ft)
            acc[mi][ft] = (f32x4){0.f, 0.f, 0.f, 0.f};

    float Xr[2][2][2][4];                    // [regbuf][bi][row][j]
    float Tr[2][8];                          // [regbuf][jj]
    float dsum = 0.0f;                       // fp32 denominator partial (m=am)

    auto load_tile = [&](int tile, int rb) { // global -> regs
        const size_t row = (size_t)(tile * TL + 2 * lp2) * Ff + fq * 4;
        *(float4*)Xr[rb][0][0] = *(const float4*)(xb0 + row);
        *(float4*)Xr[rb][0][1] = *(const float4*)(xb0 + row + Ff);
        *(float4*)Xr[rb][1][0] = *(const float4*)(xb1 + row);
        *(float4*)Xr[rb][1][1] = *(const float4*)(xb1 + row + Ff);
        *(float4*)&Tr[rb][0] = *(const float4*)&t_in[tile * TL + aq * 8];
        *(float4*)&Tr[rb][4] = *(const float4*)&t_in[tile * TL + aq * 8 + 4];
    };

    auto stage_tile = [&](int rb, int sb) {  // regs -> LDS (convert + alpha)
        #pragma unroll
        for (int bi = 0; bi < 2; ++bi)
            #pragma unroll
            for (int j = 0; j < 4; ++j) {
                const float v0 = Xr[rb][bi][0][j], v1 = Xr[rb][bi][1][j];
                const u16 h0 = bf16rne(v0), h1 = bf16rne(v1);
                const u16 s0 = bf16rne(v0 - bf16tof(h0)), s1 = bf16rne(v1 - bf16tof(h1));
                const u32 off = (u32)(bi * Ff + fq * 4 + j) * TLP + 2 * lp2;
                *(u32*)&xh_s[sb][off] = (u32)h0 | ((u32)h1 << 16);
                *(u32*)&xl_s[sb][off] = (u32)s0 | ((u32)s1 << 16);
            }
        u32 hi[4], lo[4];
        #pragma unroll
        for (int jj = 0; jj < 8; jj += 2) {
            const float u0 = __expf(Tr[rb][jj]     * ik);
            const float u1 = __expf(Tr[rb][jj + 1] * ik);
            const float a0 = u0 * __builtin_amdgcn_rcpf(fmaf(Ac, u0, 1.0f) * (u0 + Bc));
            const float a1 = u1 * __builtin_amdgcn_rcpf(fmaf(Ac, u1, 1.0f) * (u1 + Bc));
            dsum += a0 + a1;
            const u16 h0 = bf16rne(a0), h1 = bf16rne(a1);
            const u16 s0 = bf16rne(a0 - bf16tof(h0)), s1 = bf16rne(a1 - bf16tof(h1));
            hi[jj >> 1] = (u32)h0 | ((u32)h1 << 16);
            lo[jj >> 1] = (u32)s0 | ((u32)s1 << 16);
        }
        const u32 aoff = (u32)am * TLP + aq * 8;
        *(uint4*)&ah_s[sb][aoff] = make_uint4(hi[0], hi[1], hi[2], hi[3]);
        *(uint4*)&al_s[sb][aoff] = make_uint4(lo[0], lo[1], lo[2], lo[3]);
    };

    // ---- prologue: tile 0 staged; tile 1 resident in regbuf 0 ----
    load_tile(0, 0);
    stage_tile(0, 0);
    load_tile(1, 0);
    __syncthreads();

    for (int t = 0; t < NT; ++t) {
        const int cur = t & 1, nxt = cur ^ 1;

        // issue loads for tile t+2 into the free reg buffer (depth-2)
        if (t + 2 < NT) load_tile(t + 2, nxt);

        // fragment reads (12 b128) + 24 MFMA on current stage
        short8 ahf[2], alf[2], xhf[4], xlf[4];
        #pragma unroll
        for (int mi = 0; mi < 2; ++mi) {
            const u32 off = (u32)((mg * 2 + mi) * 16 + c) * TLP + q * 8;
            ahf[mi] = *(const short8*)&ah_s[cur][off];
            alf[mi] = *(const short8*)&al_s[cur][off];
        }
        #pragma unroll
        for (int ft = 0; ft < 4; ++ft) {
            const u32 off = (u32)(bw * Ff + ft * 16 + c) * TLP + q * 8;
            xhf[ft] = *(const short8*)&xh_s[cur][off];
            xlf[ft] = *(const short8*)&xl_s[cur][off];
        }
        #pragma unroll
        for (int mi = 0; mi < 2; ++mi)
            #pragma unroll
            for (int ft = 0; ft < 4; ++ft) {
                acc[mi][ft] = __builtin_amdgcn_mfma_f32_16x16x32_bf16(
                    ahf[mi], xhf[ft], acc[mi][ft], 0, 0, 0);
                acc[mi][ft] = __builtin_amdgcn_mfma_f32_16x16x32_bf16(
                    ahf[mi], xlf[ft], acc[mi][ft], 0, 0, 0);
                acc[mi][ft] = __builtin_amdgcn_mfma_f32_16x16x32_bf16(
                    alf[mi], xhf[ft], acc[mi][ft], 0, 0, 0);
            }

        // stage tile t+1 from regs loaded a full iteration ago
        if (t + 1 < NT) stage_tile(cur, nxt);
        __syncthreads();
    }

    // ---- denominator reduce (alias freed stage buf 0) ----
    float* dred = (float*)&xh_s[0][0];       // 256 f32 partials
    float* invp = dred + 256;                // 64 f32 inverses
    dred[aq * 64 + am] = dsum;
    __syncthreads();
    if (tid < Mm) {
        const float d = dred[tid] + dred[64 + tid] + dred[128 + tid] + dred[192 + tid];
        invp[tid] = 1.0f / (d + EPSV);
    }
    __syncthreads();

    // ---- epilogue: scale by 1/(denom+eps), store ----
    float* ob = out + (size_t)((b0 + bw) * Nn + n) * (Mm * Ff);
    #pragma unroll
    for (int mi = 0; mi < 2; ++mi) {
        const int mbase = (mg * 2 + mi) * 16 + q * 4;
        float iv[4];
        #pragma unroll
        for (int r = 0; r < 4; ++r) iv[r] = invp[mbase + r];
        #pragma unroll
        for (int ft = 0; ft < 4; ++ft) {
            const int f = ft * 16 + c;
            #pragma unroll
            for (int r = 0; r < 4; ++r)
                ob[(size_t)(mbase + r) * Ff + f] = acc[mi][ft][r] * iv[r];
        }
    }
}

extern "C" void kernel_launch(void* const* d_in, const int* in_sizes, int n_in,
                              void* d_out, int out_size, void* d_ws, size_t ws_size,
                              hipStream_t stream)
{
    const float* x_aug   = (const float*)d_in[0];
    const float* t_in    = (const float*)d_in[1];
    const float* t_left  = (const float*)d_in[2];
    const float* t_right = (const float*)d_in[3];
    const float* kappa   = (const float*)d_in[4];
    float* out = (float*)d_out;

    hipLaunchKernelGGL(wagg_fused, dim3((Bb / 2) * Nn), dim3(256), 0, stream,
                       x_aug, t_in, t_left, t_right, kappa, out);
}

// Round 7
// 207.536 us; speedup vs baseline: 1.1109x; 1.1109x over previous
//
#include <hip/hip_runtime.h>
#include <math.h>

typedef unsigned short u16;
typedef unsigned int   u32;
typedef __attribute__((ext_vector_type(8))) short short8;
typedef __attribute__((ext_vector_type(4))) float f32x4;

namespace {
constexpr int Bb = 32, Nn = 32, Ll = 512, Mm = 64, Ff = 64;
constexpr int TL  = 32;           // K-tile in l (= one MFMA K step)
constexpr int NT  = Ll / TL;      // 16
constexpr int TLP = 40;           // padded row (u16): 80 B stride, b128-aligned
constexpr int STG = Mm * TLP;     // 2560 u16 per array per stage
constexpr float EPSV = 1e-8f;
}

__device__ __forceinline__ u16 bf16rne(float x) {
    u32 u = __float_as_uint(x);
    return (u16)((u + 0x7fffu + ((u >> 16) & 1u)) >> 16);
}
__device__ __forceinline__ float bf16tof(u16 h) {
    return __uint_as_float(((u32)h) << 16);
}

// ---------------------------------------------------------------------------
// Fused kernel, r5 shape + 2 counter-driven fixes.
// Block = (b,n), grid 1024, 256 thr, 40 KB LDS dbuf -> 4 blocks/CU.
// Fix 1 (SQ_LDS_BANK_CONFLICT 1.1e7): x-staging remapped to fq2=tid>>4,
//   lp2b=tid&15 so ds_write_b32 banks = {0,16}+{0..15} = 2-way free.
// Fix 2 (WRITE_SIZE 131 MB vs 16.8 ideal): epilogue bounces D through LDS
//   [m][f] (stride 68) then stores coalesced float4 (1 KB/wave-instr).
// Alpha in-kernel: u=e^{t/k}, A=e^{-tr/k}, B=e^{tl/k};
//   alpha = u / ((1+A*u)(u+B)) = 1 exp + 1 rcp per element.
// ---------------------------------------------------------------------------
__global__ __launch_bounds__(256, 4)
void wagg_fused(const float* __restrict__ x_aug,
                const float* __restrict__ t_in,
                const float* __restrict__ t_left,
                const float* __restrict__ t_right,
                const float* __restrict__ kappa,
                float* __restrict__ out)
{
    const int n   = blockIdx.x & 31;
    const int b   = blockIdx.x >> 5;
    const int tid = threadIdx.x;

    // one 40 KB block, carved: per stage s: ah=+0, al=+STG, xh=+2STG, xl=+3STG
    __shared__ __align__(16) u16 smem[2 * 4 * STG];

    // ---- x staging ids (bank-conflict-free remap) ----
    const int fq2  = tid >> 4;               // f quad 0..15 (f = 4*fq2 + j)
    const int lp2b = tid & 15;               // l-pair 0..15 -> l = 2*lp2b, +1

    // ---- alpha ids: wave wv covers m in [wv*16, wv*16+16) ----
    const int wv   = tid >> 6;
    const int lane = tid & 63;
    const int ma   = wv * 16 + (lane >> 2);  // this thread's m
    const int lqa  = lane & 3;               // l octet: l = lqa*8 + 0..7

    // ---- MFMA ids: wave = (m-half, f-half), 2x2 16x16 tiles ----
    const int mh = wv & 1;                   // m base = mh*32
    const int fh = wv >> 1;                  // f base = fh*32
    const int q  = lane >> 4;                // k-chunk / D-row-quad
    const int c  = lane & 15;                // A/B row select / D-col

    const float* xb = x_aug + (size_t)(b * Nn + n) * (Ll * Ff);

    const float kap = kappa[n];
    const float kk  = fmaxf(kap, 0.0f) + log1pf(expf(-fabsf(kap))); // softplus
    const float ik  = 1.0f / kk;
    const float tlv = t_left [n * Mm + ma];
    const float trv = t_right[n * Mm + ma];
    const float Ac  = __expf(-trv * ik);     // e^{-tr/k}
    const float Bc  = __expf( tlv * ik);     // e^{+tl/k}

    f32x4 acc[2][2];
    #pragma unroll
    for (int mi = 0; mi < 2; ++mi)
        #pragma unroll
        for (int fi = 0; fi < 2; ++fi)
            acc[mi][fi] = (f32x4){0.f, 0.f, 0.f, 0.f};

    float X0[4], X1[4];                      // staged x rows (2*lp2b, 2*lp2b+1)
    float T[8];                              // staged t values
    float dsum = 0.0f;                       // fp32 denominator partial

    auto load_tile = [&](int tile) {
        const float* p = xb + (size_t)(tile * TL + 2 * lp2b) * Ff + fq2 * 4;
        *(float4*)X0 = *(const float4*)p;
        *(float4*)X1 = *(const float4*)(p + Ff);
        *(float4*)&T[0] = *(const float4*)&t_in[tile * TL + lqa * 8];
        *(float4*)&T[4] = *(const float4*)&t_in[tile * TL + lqa * 8 + 4];
    };

    auto stage_tile = [&](int buf) {
        u16* ah = smem + buf * 4 * STG;
        u16* al = ah + STG;
        u16* xh = ah + 2 * STG;
        u16* xl = ah + 3 * STG;
        // x: f32 -> bf16 hi/lo, transpose to [f][l]; 2-way banks (free)
        #pragma unroll
        for (int j = 0; j < 4; ++j) {
            const float v0 = X0[j], v1 = X1[j];
            const u16 h0 = bf16rne(v0), h1 = bf16rne(v1);
            const u16 s0 = bf16rne(v0 - bf16tof(h0)), s1 = bf16rne(v1 - bf16tof(h1));
            const u32 off = (u32)(fq2 * 4 + j) * TLP + 2 * lp2b;
            *(u32*)&xh[off] = (u32)h0 | ((u32)h1 << 16);
            *(u32*)&xl[off] = (u32)s0 | ((u32)s1 << 16);
        }
        // alpha: 8 values for (ma, l = lqa*8 + jj)
        u32 hi[4], lo[4];
        #pragma unroll
        for (int jj = 0; jj < 8; jj += 2) {
            const float u0 = __expf(T[jj]     * ik);
            const float u1 = __expf(T[jj + 1] * ik);
            const float a0 = u0 * __builtin_amdgcn_rcpf(fmaf(Ac, u0, 1.0f) * (u0 + Bc));
            const float a1 = u1 * __builtin_amdgcn_rcpf(fmaf(Ac, u1, 1.0f) * (u1 + Bc));
            dsum += a0 + a1;
            const u16 h0 = bf16rne(a0), h1 = bf16rne(a1);
            const u16 s0 = bf16rne(a0 - bf16tof(h0)), s1 = bf16rne(a1 - bf16tof(h1));
            hi[jj >> 1] = (u32)h0 | ((u32)h1 << 16);
            lo[jj >> 1] = (u32)s0 | ((u32)s1 << 16);
        }
        const u32 aoff = (u32)ma * TLP + lqa * 8;
        *(uint4*)&ah[aoff] = make_uint4(hi[0], hi[1], hi[2], hi[3]);
        *(uint4*)&al[aoff] = make_uint4(lo[0], lo[1], lo[2], lo[3]);
    };

    // ---- prologue: tile 0 ----
    load_tile(0);
    stage_tile(0);
    __syncthreads();

    for (int t = 0; t < NT; ++t) {
        const int cur = t & 1, nxt = cur ^ 1;

        if (t + 1 < NT) load_tile(t + 1);    // overlaps MFMA below

        const u16* ah = smem + cur * 4 * STG;
        const u16* al = ah + STG;
        const u16* xh = ah + 2 * STG;
        const u16* xl = ah + 3 * STG;

        short8 ahf[2], alf[2], xhf[2], xlf[2];
        #pragma unroll
        for (int mi = 0; mi < 2; ++mi) {
            const u32 off = (u32)(mh * 32 + mi * 16 + c) * TLP + q * 8;
            ahf[mi] = *(const short8*)&ah[off];
            alf[mi] = *(const short8*)&al[off];
        }
        #pragma unroll
        for (int fi = 0; fi < 2; ++fi) {
            const u32 off = (u32)(fh * 32 + fi * 16 + c) * TLP + q * 8;
            xhf[fi] = *(const short8*)&xh[off];
            xlf[fi] = *(const short8*)&xl[off];
        }
        #pragma unroll
        for (int mi = 0; mi < 2; ++mi)
            #pragma unroll
            for (int fi = 0; fi < 2; ++fi) {
                acc[mi][fi] = __builtin_amdgcn_mfma_f32_16x16x32_bf16(
                    ahf[mi], xhf[fi], acc[mi][fi], 0, 0, 0);
                acc[mi][fi] = __builtin_amdgcn_mfma_f32_16x16x32_bf16(
                    ahf[mi], xlf[fi], acc[mi][fi], 0, 0, 0);
                acc[mi][fi] = __builtin_amdgcn_mfma_f32_16x16x32_bf16(
                    alf[mi], xhf[fi], acc[mi][fi], 0, 0, 0);
            }

        if (t + 1 < NT) stage_tile(nxt);
        __syncthreads();
    }

    // ---- denominator reduce (dead upper region of stage 0) ----
    float* dred = (float*)smem + 4352;       // 256 partials (bytes 17408+)
    float* invp = dred + 256;                // 64 inverses
    dred[lqa * 64 + ma] = dsum;
    __syncthreads();
    if (tid < Mm)
        invp[tid] = 1.0f / (dred[tid] + dred[64 + tid] +
                            dred[128 + tid] + dred[192 + tid] + EPSV);
    __syncthreads();

    // ---- epilogue: scale, bounce through LDS [m][68], store coalesced ----
    float* ef = (float*)smem;                // 64 x 68 f32 = 17408 B
    #pragma unroll
    for (int mi = 0; mi < 2; ++mi) {
        const int mbase = mh * 32 + mi * 16 + q * 4;
        float iv[4];
        #pragma unroll
        for (int r = 0; r < 4; ++r) iv[r] = invp[mbase + r];
        #pragma unroll
        for (int fi = 0; fi < 2; ++fi) {
            const int f = fh * 32 + fi * 16 + c;
            #pragma unroll
            for (int r = 0; r < 4; ++r)
                ef[(mbase + r) * 68 + f] = acc[mi][fi][r] * iv[r];
        }
    }
    __syncthreads();

    float* ob = out + (size_t)(b * Nn + n) * (Mm * Ff);
    #pragma unroll
    for (int s = 0; s < 4; ++s) {
        const int idx = s * 256 + tid;       // 0..1023 float4s
        const int row = idx >> 4;
        const int col = idx & 15;
        *(float4*)&ob[row * Ff + col * 4] = *(const float4*)&ef[row * 68 + col * 4];
    }
}

extern "C" void kernel_launch(void* const* d_in, const int* in_sizes, int n_in,
                              void* d_out, int out_size, void* d_ws, size_t ws_size,
                              hipStream_t stream)
{
    const float* x_aug   = (const float*)d_in[0];
    const float* t_in    = (const float*)d_in[1];
    const float* t_left  = (const float*)d_in[2];
    const float* t_right = (const float*)d_in[3];
    const float* kappa   = (const float*)d_in[4];
    float* out = (float*)d_out;

    hipLaunchKernelGGL(wagg_fused, dim3(Bb * Nn), dim3(256), 0, stream,
                       x_aug, t_in, t_left, t_right, kappa, out);
}